// Round 1
// baseline (5005.471 us; speedup 1.0000x reference)
//
#include <hip/hip_runtime.h>
#include <stdint.h>

// Problem constants
#define LL 6
#define DM 1024
#define NH 16
#define DH 64
#define DF_ 4096
#define VV 32000
#define SS 512
#define MM 1024
#define BB 8

typedef unsigned short u16;
typedef float f32x4 __attribute__((ext_vector_type(4)));
typedef __bf16 bf16x8 __attribute__((ext_vector_type(8)));

__device__ __forceinline__ u16 f2bf(float f) {
  uint32_t u = __float_as_uint(f);
  u += 0x7fffu + ((u >> 16) & 1u);
  return (u16)(u >> 16);
}
__device__ __forceinline__ void store_bf16x4(u16* dst, f32x4 v) {
  uint32_t lo = (uint32_t)f2bf(v.x) | ((uint32_t)f2bf(v.y) << 16);
  uint32_t hi = (uint32_t)f2bf(v.z) | ((uint32_t)f2bf(v.w) << 16);
  uint2 u; u.x = lo; u.y = hi;
  *(uint2*)dst = u;
}
__device__ __forceinline__ void async_copy16(const void* g, void* l) {
  __builtin_amdgcn_global_load_lds((__attribute__((address_space(1))) void*)g,
                                   (__attribute__((address_space(3))) void*)l, 16, 0, 0);
}

// ---------------- embedding: x = input_embed[seq] + pos_embed ----------------
__global__ void embed_kernel(const int* __restrict__ seq, const float* __restrict__ emb,
                             const float* __restrict__ pos, float* __restrict__ xf,
                             u16* __restrict__ xb) {
  int row = blockIdx.x;               // B*S rows
  int c4 = threadIdx.x * 4;           // 256 threads * 4 = 1024
  int tok = seq[row];
  int s = row & (SS - 1);
  f32x4 e = *(const f32x4*)(emb + (size_t)tok * DM + c4);
  f32x4 p = *(const f32x4*)(pos + (size_t)s * DM + c4);
  f32x4 v = e + p;
  *(f32x4*)(xf + (size_t)row * DM + c4) = v;
  store_bf16x4(xb + (size_t)row * DM + c4, v);
}

// ---------------- plain fp32 -> bf16 convert ----------------
__global__ void conv_bf16(const float* __restrict__ in, u16* __restrict__ out, long n) {
  long i = ((long)blockIdx.x * 256 + threadIdx.x) * 4;
  if (i >= n) return;
  f32x4 v = *(const f32x4*)(in + i);
  store_bf16x4(out + i, v);
}

// ---------------- tiled transpose + convert fp32[R,C] -> bf16[C,R] ----------------
__global__ void transpose_conv(const float* __restrict__ in, u16* __restrict__ out,
                               int H, long in_hi, long in_lo, int in_ld,
                               long out_hi, long out_lo, int out_ld) {
  __shared__ float tile[32][33];
  int z = blockIdx.z;
  long ib = (long)(z / H) * in_hi + (long)(z % H) * in_lo;
  long ob = (long)(z / H) * out_hi + (long)(z % H) * out_lo;
  int c0 = blockIdx.x * 32, r0 = blockIdx.y * 32;
  int tx = threadIdx.x, ty = threadIdx.y; // (32,8)
#pragma unroll
  for (int i = 0; i < 4; i++)
    tile[ty + i * 8][tx] = in[ib + (long)(r0 + ty + i * 8) * in_ld + c0 + tx];
  __syncthreads();
#pragma unroll
  for (int i = 0; i < 4; i++)
    out[ob + (long)(c0 + ty + i * 8) * out_ld + r0 + tx] = f2bf(tile[tx][ty + i * 8]);
}

// ---------------- residual + LayerNorm (fp32 in/out + bf16 mirror) ----------------
__global__ void ln_kernel(const float* __restrict__ x, const float* __restrict__ r,
                          const float* __restrict__ s, const float* __restrict__ b,
                          float* __restrict__ xo, u16* __restrict__ xbo) {
  int row = blockIdx.x;
  int t = threadIdx.x; // 256
  const float* xp = x + (size_t)row * DM;
  float v[4];
  float sum = 0.f, sq = 0.f;
#pragma unroll
  for (int i = 0; i < 4; i++) {
    float a = xp[t + i * 256];
    if (r) a += r[(size_t)row * DM + t + i * 256];
    v[i] = a; sum += a; sq += a * a;
  }
  __shared__ float rs[4], rq[4], mv[2];
  int wv = t >> 6, ln = t & 63;
#pragma unroll
  for (int off = 32; off; off >>= 1) {
    sum += __shfl_xor(sum, off);
    sq  += __shfl_xor(sq, off);
  }
  if (ln == 0) { rs[wv] = sum; rq[wv] = sq; }
  __syncthreads();
  if (t == 0) {
    float ts = rs[0] + rs[1] + rs[2] + rs[3];
    float tq = rq[0] + rq[1] + rq[2] + rq[3];
    float mu = ts / DM;
    float var = tq / DM - mu * mu;
    mv[0] = mu; mv[1] = rsqrtf(var + 1e-5f);
  }
  __syncthreads();
  float mu = mv[0], rstd = mv[1];
#pragma unroll
  for (int i = 0; i < 4; i++) {
    int d = t + i * 256;
    float o = (v[i] - mu) * rstd * s[d] + b[d];
    if (xo) xo[(size_t)row * DM + d] = o;
    xbo[(size_t)row * DM + d] = f2bf(o);
  }
}

// ---------------- single-pass softmax (scale 1/8, optional causal) ----------------
// NV = Skv/64. Row cached in registers: one read of sc, one exp.
template <int NV>
__global__ void softmax_kernel(const float* __restrict__ sc, u16* __restrict__ P,
                               int causal) {
  constexpr int Skv = NV * 64;
  int row = blockIdx.x * 4 + (threadIdx.x >> 6); // z*S + q
  int ln = threadIdx.x & 63;
  int q = row & (SS - 1);
  const float* sp = sc + (size_t)row * Skv;
  int len = causal ? (q + 1) : Skv;
  float v[NV];
  float mx = -1e30f;
#pragma unroll
  for (int i = 0; i < NV; i++) {
    int idx = ln + i * 64;
    float x = (idx < len) ? sp[idx] * 0.125f : -1e30f;
    v[i] = x;
    mx = fmaxf(mx, x);
  }
#pragma unroll
  for (int off = 32; off; off >>= 1) mx = fmaxf(mx, __shfl_xor(mx, off));
  float sm = 0.f;
#pragma unroll
  for (int i = 0; i < NV; i++) {
    float e = (v[i] > -1e29f) ? __expf(v[i] - mx) : 0.f;
    v[i] = e;
    sm += e;
  }
#pragma unroll
  for (int off = 32; off; off >>= 1) sm += __shfl_xor(sm, off);
  float inv = 1.f / sm;
  u16* pp = P + (size_t)row * Skv;
#pragma unroll
  for (int i = 0; i < NV; i++) pp[ln + i * 64] = f2bf(v[i] * inv);
}

// ---------------- NT bf16 MFMA GEMM: C[m,n] = sum_k A[m,k]*B[n,k] ----------------
// LDS is XOR-swizzled in 16B chunks: slot = chunk ^ (row & (BK/8-1)).
// global_load_lds keeps linear per-lane dest; the SOURCE address is inverse-swizzled
// (rule: both-sides-or-neither), ds_read applies the same XOR.
// MODE 0: fp32 store                MODE 1: fp32 + bias[n]
// MODE 2: bf16(relu(acc+bias[n]))   MODE 3: bf16 per-head permuted store (q/k proj)
// MODE 4: bf16 store (batched addr)
// MODE 6: fused QKV epilogue: n<1024 -> Q perm (C), <2048 -> K perm (C2), else V^T (C3)
// MODE 7: fused KV  epilogue: n<1024 -> K perm (C), else V^T (C2)
// FLAGS bit0: causal block-skip (QK^T self)   FLAGS bit1: causal K-limit (PV self)
template <int BM, int BN, int BK, int MODE, int FLAGS>
__launch_bounds__(256)
__global__ void gemm_nt(const u16* __restrict__ A, const u16* __restrict__ Bm,
                        void* __restrict__ C, const float* __restrict__ bias,
                        void* __restrict__ C2, void* __restrict__ C3,
                        int M_, int N_, int K, int lda, int ldb, int ldc,
                        long batchA, long batchB, int CH, long c_hi, long c_lo,
                        int permShift) {
  constexpr int WGM = 2, WGN = 2;
  constexpr int WM = BM / WGM, WN = BN / WGN;
  constexpr int FM = WM / 16, FN = WN / 16;
  constexpr int CPR = BK / 8;      // 16B chunks per LDS row
  constexpr int SMASK = CPR - 1;
  __shared__ __align__(16) u16 As[BM * BK];
  __shared__ __align__(16) u16 Bs[BN * BK];
  int z = blockIdx.z;
  int tile_m = blockIdx.y * BM;
  int tile_n = blockIdx.x * BN;
  if ((FLAGS & 1) && tile_n >= tile_m + BM) return;   // fully-masked causal block
  const u16* Ab = A + (size_t)z * batchA;
  const u16* Bb = Bm + (size_t)z * batchB;
  int t = threadIdx.x;
  int wv = t >> 6, ln = t & 63;
  int wm = wv / WGN, wn = wv % WGN;

  f32x4 acc[FM][FN];
#pragma unroll
  for (int i = 0; i < FM; i++)
#pragma unroll
    for (int j = 0; j < FN; j++) acc[i][j] = (f32x4){0.f, 0.f, 0.f, 0.f};

  int fr_m = ln & 15;
  int hi = ln >> 4;                 // 0..3 -> which 8-elem group within 32

  int kend = (FLAGS & 2) ? (tile_m + BM < K ? tile_m + BM : K) : K;

  for (int k0 = 0; k0 < kend; k0 += BK) {
#pragma unroll
    for (int ss = 0; ss < (BM * CPR) / 256; ss++) {
      int seg = t + ss * 256;
      int row = seg / CPR;
      int cs = ((seg & SMASK) ^ (row & SMASK)) * 8;   // inverse-swizzled source
      async_copy16(Ab + (size_t)(tile_m + row) * lda + k0 + cs, (char*)As + seg * 16);
    }
#pragma unroll
    for (int ss = 0; ss < (BN * CPR) / 256; ss++) {
      int seg = t + ss * 256;
      int row = seg / CPR;
      int cs = ((seg & SMASK) ^ (row & SMASK)) * 8;
      async_copy16(Bb + (size_t)(tile_n + row) * ldb + k0 + cs, (char*)Bs + seg * 16);
    }
    __syncthreads();
#pragma unroll
    for (int kk = 0; kk < BK / 32; kk++) {
      bf16x8 af[FM], bfr[FN];
#pragma unroll
      for (int i = 0; i < FM; i++) {
        int r = wm * WM + i * 16 + fr_m;
        int c = (kk * 4 + hi) ^ (r & SMASK);          // swizzled read
        af[i] = *(const bf16x8*)&As[r * BK + c * 8];
      }
#pragma unroll
      for (int j = 0; j < FN; j++) {
        int r = wn * WN + j * 16 + fr_m;
        int c = (kk * 4 + hi) ^ (r & SMASK);
        bfr[j] = *(const bf16x8*)&Bs[r * BK + c * 8];
      }
#pragma unroll
      for (int i = 0; i < FM; i++)
#pragma unroll
        for (int j = 0; j < FN; j++)
          acc[i][j] = __builtin_amdgcn_mfma_f32_16x16x32_bf16(af[i], bfr[j], acc[i][j], 0, 0, 0);
    }
    __syncthreads();
  }

  long cbase = (long)(z / CH) * c_hi + (long)(z % CH) * c_lo;
  int col0 = tile_n + wn * WN;
  int row0 = tile_m + wm * WM;
  int cfr = ln & 15;
  int rfr = (ln >> 4) * 4;
  int pmask = (1 << permShift) - 1;
#pragma unroll
  for (int i = 0; i < FM; i++) {
#pragma unroll
    for (int j = 0; j < FN; j++) {
      int n = col0 + j * 16 + cfr;
      int m0 = row0 + i * 16 + rfr;
      if (MODE == 6 || MODE == 7) {
        int seg6 = n >> 10;          // uniform per block (BN=128 divides 1024)
        int nn = n & 1023;
        int h = nn >> 6, d = nn & 63;
        int vseg = (MODE == 6) ? 2 : 1;
        if (seg6 == vseg) {
          // V^T per-head store: vt[((b*NH+h)*64+d)*T + s], 4 s-contiguous values
          void* Cv = (MODE == 6) ? C3 : C2;
          int bb = m0 >> permShift, s0 = m0 & pmask;
          long idx = (((long)(bb * NH + h) * 64 + d) << permShift) + s0;
          store_bf16x4((u16*)Cv + idx, acc[i][j]);
        } else {
          u16* dst = (u16*)((MODE == 6 && seg6 == 1) ? C2 : C);
#pragma unroll
          for (int rr = 0; rr < 4; rr++) {
            int m = m0 + rr;
            int bb = m >> permShift, s = m & pmask;
            long idx = (((long)(bb * NH + h)) << permShift) * 64 + (long)s * 64 + d;
            dst[idx] = f2bf(acc[i][j][rr]);
          }
        }
      } else {
#pragma unroll
        for (int rr = 0; rr < 4; rr++) {
          int m = m0 + rr;
          float v = acc[i][j][rr];
          if (MODE == 0) {
            ((float*)C)[cbase + (long)m * ldc + n] = v;
          } else if (MODE == 1) {
            ((float*)C)[cbase + (long)m * ldc + n] = v + bias[n];
          } else if (MODE == 2) {
            float o = v + bias[n];
            o = o > 0.f ? o : 0.f;
            ((u16*)C)[cbase + (long)m * ldc + n] = f2bf(o);
          } else if (MODE == 3) {
            int bb = m >> permShift, s = m & pmask;
            int h = n >> 6, d = n & 63;
            long idx = (((long)(bb * NH + h)) << permShift) * 64 + (long)s * 64 + d;
            ((u16*)C)[idx] = f2bf(v);
          } else { // MODE 4
            ((u16*)C)[cbase + (long)m * ldc + n] = f2bf(v);
          }
        }
      }
    }
  }
}

extern "C" void kernel_launch(void* const* d_in, const int* in_sizes, int n_in,
                              void* d_out, int out_size, void* d_ws, size_t ws_size,
                              hipStream_t stream) {
  const float* encoded      = (const float*)d_in[0];
  const int*   seq          = (const int*)d_in[1];
  const float* input_embed  = (const float*)d_in[2];
  const float* output_embed = (const float*)d_in[3];
  const float* output_bias  = (const float*)d_in[4];
  const float* pos_embed    = (const float*)d_in[5];
  const float* Wq  = (const float*)d_in[6];
  const float* Wk  = (const float*)d_in[7];
  const float* Wv  = (const float*)d_in[8];
  const float* Wo  = (const float*)d_in[9];
  const float* Wqc = (const float*)d_in[10];
  const float* Wkc = (const float*)d_in[11];
  const float* Wvc = (const float*)d_in[12];
  const float* Woc = (const float*)d_in[13];
  const float* W1  = (const float*)d_in[14];
  const float* b1  = (const float*)d_in[15];
  const float* W2  = (const float*)d_in[16];
  const float* b2  = (const float*)d_in[17];
  const float* ln1s = (const float*)d_in[18];
  const float* ln1b = (const float*)d_in[19];
  const float* ln2s = (const float*)d_in[20];
  const float* ln2b = (const float*)d_in[21];
  const float* ln3s = (const float*)d_in[22];
  const float* ln3b = (const float*)d_in[23];
  const float* lnfs = (const float*)d_in[24];
  const float* lnfb = (const float*)d_in[25];

  char* ws = (char*)d_ws;
  size_t off = 0;
  auto alloc = [&](size_t n) { char* p = ws + off; off += (n + 255) & ~(size_t)255; return (void*)p; };

  u16* WqkvT = (u16*)alloc((size_t)LL * 3 * DM * DM * 2);  // [Wq^T;Wk^T;Wv^T] per layer
  u16* WoT   = (u16*)alloc((size_t)LL * DM * DM * 2);
  u16* WqcT  = (u16*)alloc((size_t)LL * DM * DM * 2);
  u16* WkvcT = (u16*)alloc((size_t)LL * 2 * DM * DM * 2);  // [Wkc^T;Wvc^T] per layer
  u16* WocT  = (u16*)alloc((size_t)LL * DM * DM * 2);
  u16* W1T   = (u16*)alloc((size_t)LL * DF_ * DM * 2);
  u16* W2T   = (u16*)alloc((size_t)LL * DM * DF_ * 2);
  u16* oembT = (u16*)alloc((size_t)VV * DM * 2);
  u16* encb  = (u16*)alloc((size_t)BB * MM * DM * 2);
  float* xf  = (float*)alloc((size_t)BB * SS * DM * 4);
  u16* xb    = (u16*)alloc((size_t)BB * SS * DM * 2);
  u16* qp    = (u16*)alloc((size_t)BB * SS * DM * 2);
  u16* kp    = (u16*)alloc((size_t)BB * MM * DM * 2);
  u16* vt    = (u16*)alloc((size_t)BB * MM * DM * 2);
  float* sc  = (float*)alloc((size_t)BB * NH * SS * MM * 4);
  u16* Pb    = (u16*)alloc((size_t)BB * NH * SS * MM * 2);
  u16* ob    = (u16*)alloc((size_t)BB * SS * DM * 2);
  float* attn = (float*)alloc((size_t)BB * SS * DM * 4);
  u16* hb    = (u16*)alloc((size_t)BB * SS * DF_ * 2);
  float* ffn = (float*)alloc((size_t)BB * SS * DM * 4);
  (void)ws_size; (void)in_sizes; (void)n_in; (void)out_size;

  // ---- weight conversion (every launch; inputs restored each call) ----
  // Self QKV concatenated: rows [0,1024)=Wq^T, [1024,2048)=Wk^T, [2048,3072)=Wv^T
  transpose_conv<<<dim3(32, 32, LL), dim3(32, 8), 0, stream>>>(
      Wq, WqkvT + 0 * DM * DM, 1, 1048576, 0, 1024, 3145728, 0, 1024);
  transpose_conv<<<dim3(32, 32, LL), dim3(32, 8), 0, stream>>>(
      Wk, WqkvT + 1 * DM * DM, 1, 1048576, 0, 1024, 3145728, 0, 1024);
  transpose_conv<<<dim3(32, 32, LL), dim3(32, 8), 0, stream>>>(
      Wv, WqkvT + 2 * DM * DM, 1, 1048576, 0, 1024, 3145728, 0, 1024);
  transpose_conv<<<dim3(32, 32, LL), dim3(32, 8), 0, stream>>>(
      Wo, WoT, 1, 1048576, 0, 1024, 1048576, 0, 1024);
  transpose_conv<<<dim3(32, 32, LL), dim3(32, 8), 0, stream>>>(
      Wqc, WqcT, 1, 1048576, 0, 1024, 1048576, 0, 1024);
  // Cross KV concatenated: rows [0,1024)=Wkc^T, [1024,2048)=Wvc^T
  transpose_conv<<<dim3(32, 32, LL), dim3(32, 8), 0, stream>>>(
      Wkc, WkvcT + 0 * DM * DM, 1, 1048576, 0, 1024, 2097152, 0, 1024);
  transpose_conv<<<dim3(32, 32, LL), dim3(32, 8), 0, stream>>>(
      Wvc, WkvcT + 1 * DM * DM, 1, 1048576, 0, 1024, 2097152, 0, 1024);
  transpose_conv<<<dim3(32, 32, LL), dim3(32, 8), 0, stream>>>(
      Woc, WocT, 1, 1048576, 0, 1024, 1048576, 0, 1024);
  transpose_conv<<<dim3(128, 32, LL), dim3(32, 8), 0, stream>>>(
      W1, W1T, 1, 4194304, 0, 4096, 4194304, 0, 1024);
  transpose_conv<<<dim3(32, 128, LL), dim3(32, 8), 0, stream>>>(
      W2, W2T, 1, 4194304, 0, 1024, 4194304, 0, 4096);
  conv_bf16<<<32000, 256, 0, stream>>>(output_embed, oembT, (long)VV * DM);
  conv_bf16<<<8192, 256, 0, stream>>>(encoded, encb, (long)BB * MM * DM);
  embed_kernel<<<BB * SS, 256, 0, stream>>>(seq, input_embed, pos_embed, xf, xb);

  const int Mx = BB * SS;   // 4096
  const int Me = BB * MM;   // 8192

  for (int l = 0; l < LL; l++) {
    const u16* WqkvTl = WqkvT + (size_t)l * 3 * DM * DM;
    const u16* WoTl   = WoT   + (size_t)l * DM * DM;
    const u16* WqcTl  = WqcT  + (size_t)l * DM * DM;
    const u16* WkvcTl = WkvcT + (size_t)l * 2 * DM * DM;
    const u16* WocTl  = WocT  + (size_t)l * DM * DM;

    // ---------------- self attention ----------------
    // fused QKV projection: q->qp (perm), k->kp (perm), v->vt (per-head transposed)
    gemm_nt<128,128,64,6,0><<<dim3(24,32,1),256,0,stream>>>(xb, WqkvTl, qp, nullptr, kp, vt,
        Mx,3072,1024, 1024,1024,0, 0,0, 1,0,0, 9);
    // QK^T, causal block skip, single K-shot
    gemm_nt<128,128,64,0,1><<<dim3(4,4,128),256,0,stream>>>(qp, kp, sc, nullptr, nullptr, nullptr,
        512,512,64, 64,64,512, 32768,32768, 1,262144,0, 0);
    softmax_kernel<8><<<16384,256,0,stream>>>(sc, Pb, 1);
    // PV with causal K-limit
    gemm_nt<128,64,64,4,2><<<dim3(1,4,128),256,0,stream>>>(Pb, vt, ob, nullptr, nullptr, nullptr,
        512,64,512, 512,512,1024, 262144,32768, 16,524288,64, 0);
    gemm_nt<64,128,64,0,0><<<dim3(8,64,1),256,0,stream>>>(ob, WoTl, attn, nullptr, nullptr, nullptr,
        Mx,1024,1024, 1024,1024,1024, 0,0, 1,0,0, 0);
    ln_kernel<<<Mx,256,0,stream>>>(xf, attn, ln1s + l*DM, ln1b + l*DM, xf, xb);

    // ---------------- cross attention ----------------
    gemm_nt<64,128,64,3,0><<<dim3(8,64,1),256,0,stream>>>(xb, WqcTl, qp, nullptr, nullptr, nullptr,
        Mx,1024,1024, 1024,1024,0, 0,0, 1,0,0, 9);
    // fused KV projection on encoded: k->kp (perm), v->vt
    gemm_nt<128,128,64,7,0><<<dim3(16,64,1),256,0,stream>>>(encb, WkvcTl, kp, nullptr, vt, nullptr,
        Me,2048,1024, 1024,1024,0, 0,0, 1,0,0, 10);
    gemm_nt<128,128,64,0,0><<<dim3(8,4,128),256,0,stream>>>(qp, kp, sc, nullptr, nullptr, nullptr,
        512,1024,64, 64,64,1024, 32768,65536, 1,524288,0, 0);
    softmax_kernel<16><<<16384,256,0,stream>>>(sc, Pb, 0);
    gemm_nt<128,64,64,4,0><<<dim3(1,4,128),256,0,stream>>>(Pb, vt, ob, nullptr, nullptr, nullptr,
        512,64,1024, 1024,1024,1024, 524288,65536, 16,524288,64, 0);
    gemm_nt<64,128,64,0,0><<<dim3(8,64,1),256,0,stream>>>(ob, WocTl, attn, nullptr, nullptr, nullptr,
        Mx,1024,1024, 1024,1024,1024, 0,0, 1,0,0, 0);
    ln_kernel<<<Mx,256,0,stream>>>(xf, attn, ln2s + l*DM, ln2b + l*DM, xf, xb);

    // ---------------- FFN ----------------
    gemm_nt<128,128,64,2,0><<<dim3(32,32,1),256,0,stream>>>(xb, W1T + (size_t)l*DF_*DM, hb,
        b1 + (size_t)l*DF_, nullptr, nullptr, Mx,4096,1024, 1024,1024,4096, 0,0, 1,0,0, 0);
    gemm_nt<64,128,64,1,0><<<dim3(8,64,1),256,0,stream>>>(hb, W2T + (size_t)l*DM*DF_, ffn,
        b2 + (size_t)l*DM, nullptr, nullptr, Mx,1024,4096, 4096,4096,1024, 0,0, 1,0,0, 0);
    ln_kernel<<<Mx,256,0,stream>>>(xf, ffn, ln3s + l*DM, ln3b + l*DM, xf, xb);
  }

  // final norm + vocab projection
  ln_kernel<<<Mx,256,0,stream>>>(xf, nullptr, lnfs, lnfb, xf, xb);
  gemm_nt<128,128,64,1,0><<<dim3(250,32,1),256,0,stream>>>(xb, oembT, (float*)d_out,
      output_bias, nullptr, nullptr, Mx,32000,1024, 1024,1024,32000, 0,0, 1,0,0, 0);
}